// Round 3
// baseline (452.178 us; speedup 1.0000x reference)
//
#include <hip/hip_runtime.h>
#include <math.h>

#define F 128
#define ZD 272
#define EDIM 16
#define EPS 1e-5f

// ---------------------------------------------------------------------------
// Kernel A: node tables. Layout per node (512 floats):
//   [0:128)   dst-filter (+bf)
//   [128:256) dst-softplus (+bs)
//   [256:512) src interleaved: {srcF[f], srcS[f]} pairs -> float2 gather
// ---------------------------------------------------------------------------
__global__ __launch_bounds__(256) void node_gemm(
    const float* __restrict__ x, const float* __restrict__ Wf,
    const float* __restrict__ Ws, const float* __restrict__ bf,
    const float* __restrict__ bs, float* __restrict__ tab, int N)
{
  __shared__ float As[64][76];  // [k][m]
  __shared__ float Bs[64][76];  // [k][n]
  const int bm = blockIdx.x, bn = blockIdx.y;
  const int t = bn >> 1;                 // 0..3
  const int fbase = (bn & 1) * 64;       // 0 or 64
  const float* W = (t & 1) ? Ws : Wf;
  const int koff = (t >= 2) ? F : 0;
  const int tid = threadIdx.x;
  const int kq = (tid & 15) * 4;
  const int rr = tid >> 4;

  const int tx = tid & 15, ty = tid >> 4;
  const int m0 = ty * 4, n0 = tx * 4;
  float acc[4][4] = {};

  for (int kk = 0; kk < F; kk += 64) {
    #pragma unroll
    for (int it = 0; it < 4; ++it) {
      int row = it * 16 + rr;
      int node = bm * 64 + row;
      float4 v = make_float4(0.f, 0.f, 0.f, 0.f);
      if (node < N) v = *(const float4*)(x + (size_t)node * F + kk + kq);
      As[kq + 0][row] = v.x; As[kq + 1][row] = v.y;
      As[kq + 2][row] = v.z; As[kq + 3][row] = v.w;
    }
    #pragma unroll
    for (int it = 0; it < 4; ++it) {
      int n = it * 16 + rr;
      float4 v = *(const float4*)(W + (size_t)(fbase + n) * ZD + koff + kk + kq);
      Bs[kq + 0][n] = v.x; Bs[kq + 1][n] = v.y;
      Bs[kq + 2][n] = v.z; Bs[kq + 3][n] = v.w;
    }
    __syncthreads();
    #pragma unroll 8
    for (int k = 0; k < 64; ++k) {
      float4 a = *(const float4*)&As[k][m0];
      float4 b = *(const float4*)&Bs[k][n0];
      float av[4] = {a.x, a.y, a.z, a.w};
      float bv[4] = {b.x, b.y, b.z, b.w};
      #pragma unroll
      for (int i = 0; i < 4; ++i)
        #pragma unroll
        for (int j = 0; j < 4; ++j)
          acc[i][j] += av[i] * bv[j];
    }
    __syncthreads();
  }

  #pragma unroll
  for (int i = 0; i < 4; ++i) {
    int node = bm * 64 + m0 + i;
    if (node >= N) continue;
    const size_t nb = (size_t)node * 512;
    #pragma unroll
    for (int j = 0; j < 4; ++j) {
      int f = fbase + n0 + j;
      float v = acc[i][j];
      if (t == 0)      tab[nb + f] = v + bf[f];
      else if (t == 1) tab[nb + F + f] = v + bs[f];
      else             tab[nb + 2 * F + 2 * f + (t - 2)] = v;
    }
  }
}

// ---------------------------------------------------------------------------
// CSR build
// ---------------------------------------------------------------------------
__global__ void count_deg(const int* __restrict__ dst, int* __restrict__ cnt, int E)
{
  int e = blockIdx.x * blockDim.x + threadIdx.x;
  if (e < E) atomicAdd(&cnt[dst[e]], 1);
}

__global__ __launch_bounds__(1024) void scan_k(
    const int* __restrict__ cnt, int* __restrict__ rowptr,
    int* __restrict__ cursor, int N, int cpt)
{
  __shared__ int lds[1024];
  const int tid = threadIdx.x;
  const int base = tid * cpt;
  int run = 0;
  for (int j = 0; j < cpt; ++j) {
    int idx = base + j;
    run += (idx < N) ? cnt[idx] : 0;
  }
  lds[tid] = run;
  __syncthreads();
  for (int off = 1; off < 1024; off <<= 1) {
    int v = (tid >= off) ? lds[tid - off] : 0;
    __syncthreads();
    lds[tid] += v;
    __syncthreads();
  }
  int v = lds[tid] - run;
  for (int j = 0; j < cpt; ++j) {
    int idx = base + j;
    if (idx <= N) {
      rowptr[idx] = v;
      if (idx < N) { cursor[idx] = v; v += cnt[idx]; }
    }
  }
}

// Permuting fill: also copies edge_attr into CSR order (sequential reads later)
__global__ void fill_csr2(const int* __restrict__ dst, const int* __restrict__ srcA,
                          const float* __restrict__ ea, int* __restrict__ cursor,
                          int* __restrict__ srcs, float* __restrict__ eap, int E)
{
  int e = blockIdx.x * blockDim.x + threadIdx.x;
  if (e < E) {
    int pos = atomicAdd(&cursor[dst[e]], 1);
    srcs[pos] = srcA[e];
    const float4* s4 = (const float4*)(ea + (size_t)e * EDIM);
    float4 a = s4[0], b = s4[1], c = s4[2], d = s4[3];
    float4* d4 = (float4*)(eap + (size_t)pos * EDIM);
    d4[0] = a; d4[1] = b; d4[2] = c; d4[3] = d;
  }
}

// Fallback fill (no eaPerm) if ws too small
__global__ void fill_csr(const int* __restrict__ dst, const int* __restrict__ srcA,
                         int* __restrict__ cursor, int* __restrict__ eids,
                         int* __restrict__ srcs, int E)
{
  int e = blockIdx.x * blockDim.x + threadIdx.x;
  if (e < E) {
    int pos = atomicAdd(&cursor[dst[e]], 1);
    eids[pos] = e;
    srcs[pos] = srcA[e];
  }
}

// ---------------------------------------------------------------------------
// Aggregation
// ---------------------------------------------------------------------------
__device__ __forceinline__ float sigm(float v) {
  return __builtin_amdgcn_rcpf(1.f + __expf(-v));
}
__device__ __forceinline__ float splus(float v) {
  return fmaxf(v, 0.f) + __logf(1.f + __expf(-fabsf(v)));
}

struct W16 { float w[16]; };

__device__ __forceinline__ float edge_msg(
    float pdf, float pds, float2 sv, float4 e0, const float4* e4,
    const W16& wf, const W16& ws)
{
  float af = pdf + sv.x;
  float as = pds + sv.y;
  af += wf.w[0]*e0.x + wf.w[1]*e0.y + wf.w[2]*e0.z + wf.w[3]*e0.w;
  as += ws.w[0]*e0.x + ws.w[1]*e0.y + ws.w[2]*e0.z + ws.w[3]*e0.w;
  #pragma unroll
  for (int q = 1; q < 4; ++q) {
    float4 v = e4[q];
    af += wf.w[4*q]*v.x + wf.w[4*q+1]*v.y + wf.w[4*q+2]*v.z + wf.w[4*q+3]*v.w;
    as += ws.w[4*q]*v.x + ws.w[4*q+1]*v.y + ws.w[4*q+2]*v.z + ws.w[4*q+3]*v.w;
  }
  return sigm(af) * splus(as);
}

// Sequential-ea variant: depth-4 batched sv gathers + streaming eaPerm
__global__ __launch_bounds__(256, 4) void aggregate_seq(
    const float* __restrict__ tab, const float* __restrict__ eap,
    const int* __restrict__ srcs, const int* __restrict__ rowptr,
    const float* __restrict__ Wf, const float* __restrict__ Ws,
    float* __restrict__ agg, int N)
{
  const int lane = threadIdx.x & 63;
  const int unit = (blockIdx.x * blockDim.x + threadIdx.x) >> 6;
  const int node = unit >> 1;
  if (node >= N) return;
  const int f = ((unit & 1) << 6) | lane;

  W16 wf, ws;
  #pragma unroll
  for (int q = 0; q < 4; ++q) {
    float4 a = ((const float4*)(Wf + (size_t)f * ZD + 2 * F))[q];
    wf.w[4*q] = a.x; wf.w[4*q+1] = a.y; wf.w[4*q+2] = a.z; wf.w[4*q+3] = a.w;
    float4 b = ((const float4*)(Ws + (size_t)f * ZD + 2 * F))[q];
    ws.w[4*q] = b.x; ws.w[4*q+1] = b.y; ws.w[4*q+2] = b.z; ws.w[4*q+3] = b.w;
  }

  const size_t nb = (size_t)node * 512;
  const float pdf = tab[nb + f];
  const float pds = tab[nb + F + f];
  const float* svb = tab + 2 * F + 2 * f;   // + src*512
  const int s = rowptr[node], e = rowptr[node + 1];
  const float4* ep = (const float4*)(eap + (size_t)s * EDIM);
  float acc = 0.f;

  int p = s;
  for (; p + 4 <= e; p += 4, ep += 16) {
    int s0 = srcs[p], s1 = srcs[p+1], s2 = srcs[p+2], s3 = srcs[p+3];
    float2 v0 = *(const float2*)(svb + (size_t)s0 * 512);
    float2 v1 = *(const float2*)(svb + (size_t)s1 * 512);
    float2 v2 = *(const float2*)(svb + (size_t)s2 * 512);
    float2 v3 = *(const float2*)(svb + (size_t)s3 * 512);
    float4 e0a = ep[0], e0b = ep[4], e0c = ep[8], e0d = ep[12];
    acc += edge_msg(pdf, pds, v0, e0a, ep,      wf, ws);
    acc += edge_msg(pdf, pds, v1, e0b, ep + 4,  wf, ws);
    acc += edge_msg(pdf, pds, v2, e0c, ep + 8,  wf, ws);
    acc += edge_msg(pdf, pds, v3, e0d, ep + 12, wf, ws);
  }
  for (; p < e; ++p, ep += 4) {
    int s0 = srcs[p];
    float2 v0 = *(const float2*)(svb + (size_t)s0 * 512);
    float4 e0a = ep[0];
    acc += edge_msg(pdf, pds, v0, e0a, ep, wf, ws);
  }
  agg[(size_t)node * F + f] = acc;
}

// Fallback gather variant (round-2 style)
__global__ __launch_bounds__(256, 4) void aggregate_gat(
    const float* __restrict__ tab, const float* __restrict__ ea,
    const int* __restrict__ eids, const int* __restrict__ srcs,
    const int* __restrict__ rowptr, const float* __restrict__ Wf,
    const float* __restrict__ Ws, float* __restrict__ agg, int N)
{
  const int lane = threadIdx.x & 63;
  const int unit = (blockIdx.x * blockDim.x + threadIdx.x) >> 6;
  const int node = unit >> 1;
  if (node >= N) return;
  const int f = ((unit & 1) << 6) | lane;

  W16 wf, ws;
  #pragma unroll
  for (int q = 0; q < 4; ++q) {
    float4 a = ((const float4*)(Wf + (size_t)f * ZD + 2 * F))[q];
    wf.w[4*q] = a.x; wf.w[4*q+1] = a.y; wf.w[4*q+2] = a.z; wf.w[4*q+3] = a.w;
    float4 b = ((const float4*)(Ws + (size_t)f * ZD + 2 * F))[q];
    ws.w[4*q] = b.x; ws.w[4*q+1] = b.y; ws.w[4*q+2] = b.z; ws.w[4*q+3] = b.w;
  }

  const size_t nb = (size_t)node * 512;
  const float pdf = tab[nb + f];
  const float pds = tab[nb + F + f];
  const float* svb = tab + 2 * F + 2 * f;
  float acc = 0.f;
  const int s = rowptr[node], e = rowptr[node + 1];
  #pragma unroll 2
  for (int p = s; p < e; ++p) {
    const int eid = eids[p];
    const int src = srcs[p];
    const float2 sv = *(const float2*)(svb + (size_t)src * 512);
    const float4* e4 = (const float4*)(ea + (size_t)eid * EDIM);
    float4 e0 = e4[0];
    acc += edge_msg(pdf, pds, sv, e0, e4, wf, ws);
  }
  agg[(size_t)node * F + f] = acc;
}

// ---------------------------------------------------------------------------
__global__ __launch_bounds__(256) void bn_stats(
    const float* __restrict__ agg, float* __restrict__ sums, int N)
{
  const int f = threadIdx.x & 127;
  const int h = threadIdx.x >> 7;
  float s = 0.f, ss = 0.f;
  for (int r = blockIdx.x * 2 + h; r < N; r += gridDim.x * 2) {
    float v = agg[(size_t)r * F + f];
    s += v; ss += v * v;
  }
  atomicAdd(&sums[f], s);
  atomicAdd(&sums[F + f], ss);
}

__global__ __launch_bounds__(256) void finalize(
    const float* __restrict__ x, float* __restrict__ out,
    const float* __restrict__ sums, const float* __restrict__ bng,
    const float* __restrict__ bnb, const float* __restrict__ lng,
    const float* __restrict__ lnb, int N)
{
  const int lane = threadIdx.x & 63;
  const int wid  = (blockIdx.x * blockDim.x + threadIdx.x) >> 6;
  const int nwav = (gridDim.x * blockDim.x) >> 6;
  const int f0 = lane, f1 = lane + 64;
  const float invN = 1.f / (float)N;

  float mu0 = sums[f0] * invN, vv0 = sums[F + f0] * invN - mu0 * mu0;
  float mu1 = sums[f1] * invN, vv1 = sums[F + f1] * invN - mu1 * mu1;
  float sc0 = rsqrtf(vv0 + EPS) * bng[f0], sh0 = bnb[f0] - mu0 * sc0;
  float sc1 = rsqrtf(vv1 + EPS) * bng[f1], sh1 = bnb[f1] - mu1 * sc1;
  float g0 = lng[f0], g1 = lng[f1], be0 = lnb[f0], be1 = lnb[f1];

  for (int node = wid; node < N; node += nwav) {
    const size_t b = (size_t)node * F;
    float x0 = x[b + f0], x1 = x[b + f1];
    float h0 = out[b + f0] * sc0 + sh0 + x0;
    float h1 = out[b + f1] * sc1 + sh1 + x1;
    float s = h0 + h1, q = h0 * h0 + h1 * h1;
    #pragma unroll
    for (int o = 32; o > 0; o >>= 1) {
      s += __shfl_xor(s, o, 64);
      q += __shfl_xor(q, o, 64);
    }
    float mu = s * (1.f / 128.f);
    float var = q * (1.f / 128.f) - mu * mu;
    float rs = rsqrtf(var + EPS);
    float y0 = fmaxf((h0 - mu) * rs * g0 + be0, 0.f) + x0;
    float y1 = fmaxf((h1 - mu) * rs * g1 + be1, 0.f) + x1;
    out[b + f0] = y0;
    out[b + f1] = y1;
  }
}

// ---------------------------------------------------------------------------
extern "C" void kernel_launch(void* const* d_in, const int* in_sizes, int n_in,
                              void* d_out, int out_size, void* d_ws, size_t ws_size,
                              hipStream_t stream)
{
  const float* x   = (const float*)d_in[0];
  const int*   ei  = (const int*)d_in[1];
  const float* ea  = (const float*)d_in[2];
  const float* Wf  = (const float*)d_in[3];
  const float* bf  = (const float*)d_in[4];
  const float* Ws  = (const float*)d_in[5];
  const float* bs  = (const float*)d_in[6];
  const float* bng = (const float*)d_in[7];
  const float* bnb = (const float*)d_in[8];
  const float* lng = (const float*)d_in[9];
  const float* lnb = (const float*)d_in[10];

  const int N = in_sizes[0] / F;
  const int E = in_sizes[1] / 2;
  const int* srcA = ei;
  const int* dstA = ei + E;
  float* out = (float*)d_out;

  char* w = (char*)d_ws;
  size_t off = 0;
  auto up = [](size_t v) { return (v + 255) & ~(size_t)255; };
  float* tab    = (float*)(w + off); off = up(off + (size_t)N * 512 * sizeof(float));
  int*   srcs   = (int*)(w + off);   off = up(off + (size_t)E * sizeof(int));
  int*   rowptr = (int*)(w + off);   off = up(off + (size_t)(N + 1) * sizeof(int));
  int*   cursor = (int*)(w + off);   off = up(off + (size_t)N * sizeof(int));
  int*   cnt    = (int*)(w + off);   off = up(off + (size_t)N * sizeof(int));
  float* sums   = (float*)(w + off); off = up(off + 256 * sizeof(float));
  size_t base_need = off;
  float* eap    = (float*)(w + off);
  size_t need_seq = off + (size_t)E * EDIM * sizeof(float);
  int*   eids   = (int*)(w + off);   // fallback aliases same region
  size_t need_gat = off + (size_t)E * sizeof(int);
  const bool use_seq = (ws_size >= need_seq);

  hipMemsetAsync(cnt, 0, (size_t)N * sizeof(int), stream);
  hipMemsetAsync(sums, 0, 256 * sizeof(float), stream);

  node_gemm<<<dim3((N + 63) / 64, 8), 256, 0, stream>>>(x, Wf, Ws, bf, bs, tab, N);
  count_deg<<<(E + 255) / 256, 256, 0, stream>>>(dstA, cnt, E);
  const int cpt = (N + 1 + 1023) / 1024;
  scan_k<<<1, 1024, 0, stream>>>(cnt, rowptr, cursor, N, cpt);

  const int units = 2 * N;
  if (use_seq) {
    fill_csr2<<<(E + 255) / 256, 256, 0, stream>>>(dstA, srcA, ea, cursor, srcs, eap, E);
    aggregate_seq<<<(units + 3) / 4, 256, 0, stream>>>(tab, eap, srcs, rowptr, Wf, Ws, out, N);
  } else if (ws_size >= need_gat) {
    fill_csr<<<(E + 255) / 256, 256, 0, stream>>>(dstA, srcA, cursor, eids, srcs, E);
    aggregate_gat<<<(units + 3) / 4, 256, 0, stream>>>(tab, ea, eids, srcs, rowptr, Wf, Ws, out, N);
  }
  (void)base_need;

  bn_stats<<<256, 256, 0, stream>>>(out, sums, N);
  finalize<<<(N + 3) / 4, 256, 0, stream>>>(x, out, sums, bng, bnb, lng, lnb, N);
}

// Round 4
// 441.903 us; speedup vs baseline: 1.0233x; 1.0233x over previous
//
#include <hip/hip_runtime.h>
#include <math.h>

#define F 128
#define ZD 272
#define EDIM 16
#define EPS 1e-5f

typedef unsigned int uint32;

__device__ __forceinline__ uint32 f2bf(float a) {
  uint32 u = __float_as_uint(a);
  u += 0x7FFF + ((u >> 16) & 1);   // RNE
  return u >> 16;
}

// ---------------------------------------------------------------------------
// Kernel A: node tables.
//   tabdst[n][0:128)   dst-filter (+bf)      f32
//   tabdst[n][128:256) dst-softplus (+bs)    f32
//   stg[n][0:128) srcF, stg[n][128:256) srcS f32 (staging, packed later)
// ---------------------------------------------------------------------------
__global__ __launch_bounds__(256) void node_gemm(
    const float* __restrict__ x, const float* __restrict__ Wf,
    const float* __restrict__ Ws, const float* __restrict__ bf,
    const float* __restrict__ bs, float* __restrict__ tabdst,
    float* __restrict__ stg, int N)
{
  __shared__ float As[64][76];  // [k][m]
  __shared__ float Bs[64][76];  // [k][n]
  const int bm = blockIdx.x, bn = blockIdx.y;
  const int t = bn >> 1;                 // 0..3
  const int fbase = (bn & 1) * 64;       // 0 or 64
  const float* W = (t & 1) ? Ws : Wf;
  const int koff = (t >= 2) ? F : 0;
  const int tid = threadIdx.x;
  const int kq = (tid & 15) * 4;
  const int rr = tid >> 4;

  const int tx = tid & 15, ty = tid >> 4;
  const int m0 = ty * 4, n0 = tx * 4;
  float acc[4][4] = {};

  for (int kk = 0; kk < F; kk += 64) {
    #pragma unroll
    for (int it = 0; it < 4; ++it) {
      int row = it * 16 + rr;
      int node = bm * 64 + row;
      float4 v = make_float4(0.f, 0.f, 0.f, 0.f);
      if (node < N) v = *(const float4*)(x + (size_t)node * F + kk + kq);
      As[kq + 0][row] = v.x; As[kq + 1][row] = v.y;
      As[kq + 2][row] = v.z; As[kq + 3][row] = v.w;
    }
    #pragma unroll
    for (int it = 0; it < 4; ++it) {
      int n = it * 16 + rr;
      float4 v = *(const float4*)(W + (size_t)(fbase + n) * ZD + koff + kk + kq);
      Bs[kq + 0][n] = v.x; Bs[kq + 1][n] = v.y;
      Bs[kq + 2][n] = v.z; Bs[kq + 3][n] = v.w;
    }
    __syncthreads();
    #pragma unroll 8
    for (int k = 0; k < 64; ++k) {
      float4 a = *(const float4*)&As[k][m0];
      float4 b = *(const float4*)&Bs[k][n0];
      float av[4] = {a.x, a.y, a.z, a.w};
      float bv[4] = {b.x, b.y, b.z, b.w};
      #pragma unroll
      for (int i = 0; i < 4; ++i)
        #pragma unroll
        for (int j = 0; j < 4; ++j)
          acc[i][j] += av[i] * bv[j];
    }
    __syncthreads();
  }

  #pragma unroll
  for (int i = 0; i < 4; ++i) {
    int node = bm * 64 + m0 + i;
    if (node >= N) continue;
    const size_t nb = (size_t)node * 256;
    #pragma unroll
    for (int j = 0; j < 4; ++j) {
      int f = fbase + n0 + j;
      float v = acc[i][j];
      if (t == 0)      tabdst[nb + f] = v + bf[f];
      else if (t == 1) tabdst[nb + F + f] = v + bs[f];
      else if (t == 2) stg[nb + f] = v;
      else             stg[nb + F + f] = v;
    }
  }
}

// Pack src tables: {srcF,srcS} -> one u32 of two bf16
__global__ __launch_bounds__(256) void pack_src(
    const float* __restrict__ stg, uint32* __restrict__ tabsrc, int total)
{
  int i = blockIdx.x * blockDim.x + threadIdx.x;
  if (i < total) {
    int n = i >> 7, f = i & 127;
    float sf = stg[(size_t)n * 256 + f];
    float ss = stg[(size_t)n * 256 + F + f];
    tabsrc[i] = f2bf(sf) | (f2bf(ss) << 16);
  }
}

// ---------------------------------------------------------------------------
// CSR build
// ---------------------------------------------------------------------------
__global__ void count_deg(const int* __restrict__ dst, int* __restrict__ cnt, int E)
{
  int e = blockIdx.x * blockDim.x + threadIdx.x;
  if (e < E) atomicAdd(&cnt[dst[e]], 1);
}

__global__ __launch_bounds__(1024) void scan_k(
    const int* __restrict__ cnt, int* __restrict__ cursor, int N, int cpt)
{
  __shared__ int lds[1024];
  const int tid = threadIdx.x;
  const int base = tid * cpt;
  int run = 0;
  for (int j = 0; j < cpt; ++j) {
    int idx = base + j;
    run += (idx < N) ? cnt[idx] : 0;
  }
  lds[tid] = run;
  __syncthreads();
  for (int off = 1; off < 1024; off <<= 1) {
    int v = (tid >= off) ? lds[tid - off] : 0;
    __syncthreads();
    lds[tid] += v;
    __syncthreads();
  }
  int v = lds[tid] - run;
  for (int j = 0; j < cpt; ++j) {
    int idx = base + j;
    if (idx < N) { cursor[idx] = v; v += cnt[idx]; }
  }
}

// Permuting fill: srcs/dstp/edge-attr into CSR (dst-sorted) order
__global__ void fill_csr2(const int* __restrict__ dst, const int* __restrict__ srcA,
                          const float* __restrict__ ea, int* __restrict__ cursor,
                          int* __restrict__ srcs, int* __restrict__ dstp,
                          float* __restrict__ eap, int E)
{
  int e = blockIdx.x * blockDim.x + threadIdx.x;
  if (e < E) {
    int d = dst[e];
    int pos = atomicAdd(&cursor[d], 1);
    srcs[pos] = srcA[e];
    dstp[pos] = d;
    const float4* s4 = (const float4*)(ea + (size_t)e * EDIM);
    float4 a = s4[0], b = s4[1], c = s4[2], dd = s4[3];
    float4* d4 = (float4*)(eap + (size_t)pos * EDIM);
    d4[0] = a; d4[1] = b; d4[2] = c; d4[3] = dd;
  }
}

// ---------------------------------------------------------------------------
// Aggregation: edge-balanced. Each wave owns C consecutive CSR slots for one
// feature-half; register-accumulates same-dst runs; atomicAdd on dst change.
// Gathers for batch k+1 issued before computing batch k (srcs 2 batches ahead).
// ---------------------------------------------------------------------------
__device__ __forceinline__ float sigm(float v) {
  return __builtin_amdgcn_rcpf(1.f + __expf(-v));
}
__device__ __forceinline__ float splus(float v) {
  return fmaxf(v, 0.f) + __logf(1.f + __expf(-fabsf(v)));
}

struct W16 { float w[16]; };

__global__ __launch_bounds__(256, 4) void aggregate_ebal(
    const float* __restrict__ tabdst, const uint32* __restrict__ tabsrc,
    const float* __restrict__ eap, const int* __restrict__ srcs,
    const int* __restrict__ dstp, const float* __restrict__ Wf,
    const float* __restrict__ Ws, float* __restrict__ agg, int E, int C)
{
  const int lane = threadIdx.x & 63;
  const int wid  = (blockIdx.x * blockDim.x + threadIdx.x) >> 6;
  const int half = wid & 1;
  const int chunk = wid >> 1;
  const int p0 = chunk * C;
  int p1 = p0 + C; if (p1 > E) p1 = E;
  if (p0 >= p1) return;
  const int f = (half << 6) | lane;

  W16 wf, ws;
  #pragma unroll
  for (int q = 0; q < 4; ++q) {
    float4 a = ((const float4*)(Wf + (size_t)f * ZD + 2 * F))[q];
    wf.w[4*q] = a.x; wf.w[4*q+1] = a.y; wf.w[4*q+2] = a.z; wf.w[4*q+3] = a.w;
    float4 b = ((const float4*)(Ws + (size_t)f * ZD + 2 * F))[q];
    ws.w[4*q] = b.x; ws.w[4*q+1] = b.y; ws.w[4*q+2] = b.z; ws.w[4*q+3] = b.w;
  }

  const uint32* svb = tabsrc + f;

  int curDst = dstp[p0];
  float pdf = tabdst[(size_t)curDst * 256 + f];
  float pds = tabdst[(size_t)curDst * 256 + F + f];
  float acc = 0.f;

  // prologue: batch at p0 issued; srcs for p0+4 loaded
  int4 sA = *(const int4*)(srcs + p0);
  uint32 svc[4], svn[4];
  {
    const int* sa = (const int*)&sA;
    #pragma unroll
    for (int i = 0; i < 4; ++i) {
      int s = (p0 + i < p1) ? sa[i] : 0;
      svc[i] = svb[(size_t)s * F];
    }
  }
  int4 sB = *(const int4*)(srcs + p0 + 4);

  for (int p = p0; p < p1; p += 4) {
    const int pn = p + 4;
    // issue next batch's gathers (independent of current compute)
    {
      const int* sb = (const int*)&sB;
      #pragma unroll
      for (int i = 0; i < 4; ++i) {
        int s = (pn + i < p1) ? sb[i] : 0;
        svn[i] = svb[(size_t)s * F];
      }
    }
    int4 sC = *(const int4*)(srcs + pn + 4);

    // compute current batch
    #pragma unroll
    for (int i = 0; i < 4; ++i) {
      if (p + i >= p1) break;
      int d = dstp[p + i];
      if (d != curDst) {
        atomicAdd(&agg[(size_t)curDst * F + f], acc);
        acc = 0.f;
        curDst = d;
        pdf = tabdst[(size_t)d * 256 + f];
        pds = tabdst[(size_t)d * 256 + F + f];
      }
      uint32 pk = svc[i];
      float sf = __uint_as_float(pk << 16);
      float ss = __uint_as_float(pk & 0xFFFF0000u);
      const float4* e4 = (const float4*)(eap + (size_t)(p + i) * EDIM);
      float af = pdf + sf;
      float as = pds + ss;
      #pragma unroll
      for (int q = 0; q < 4; ++q) {
        float4 v = e4[q];
        af += wf.w[4*q]*v.x + wf.w[4*q+1]*v.y + wf.w[4*q+2]*v.z + wf.w[4*q+3]*v.w;
        as += ws.w[4*q]*v.x + ws.w[4*q+1]*v.y + ws.w[4*q+2]*v.z + ws.w[4*q+3]*v.w;
      }
      acc += sigm(af) * splus(as);
    }

    svc[0] = svn[0]; svc[1] = svn[1]; svc[2] = svn[2]; svc[3] = svn[3];
    sB = sC;
  }
  atomicAdd(&agg[(size_t)curDst * F + f], acc);
}

// ---------------------------------------------------------------------------
__global__ __launch_bounds__(256) void bn_stats(
    const float* __restrict__ agg, float* __restrict__ sums, int N)
{
  const int f = threadIdx.x & 127;
  const int h = threadIdx.x >> 7;
  float s = 0.f, ss = 0.f;
  for (int r = blockIdx.x * 2 + h; r < N; r += gridDim.x * 2) {
    float v = agg[(size_t)r * F + f];
    s += v; ss += v * v;
  }
  atomicAdd(&sums[f], s);
  atomicAdd(&sums[F + f], ss);
}

__global__ __launch_bounds__(256) void finalize(
    const float* __restrict__ x, float* __restrict__ out,
    const float* __restrict__ sums, const float* __restrict__ bng,
    const float* __restrict__ bnb, const float* __restrict__ lng,
    const float* __restrict__ lnb, int N)
{
  const int lane = threadIdx.x & 63;
  const int wid  = (blockIdx.x * blockDim.x + threadIdx.x) >> 6;
  const int nwav = (gridDim.x * blockDim.x) >> 6;
  const int f0 = lane, f1 = lane + 64;
  const float invN = 1.f / (float)N;

  float mu0 = sums[f0] * invN, vv0 = sums[F + f0] * invN - mu0 * mu0;
  float mu1 = sums[f1] * invN, vv1 = sums[F + f1] * invN - mu1 * mu1;
  float sc0 = rsqrtf(vv0 + EPS) * bng[f0], sh0 = bnb[f0] - mu0 * sc0;
  float sc1 = rsqrtf(vv1 + EPS) * bng[f1], sh1 = bnb[f1] - mu1 * sc1;
  float g0 = lng[f0], g1 = lng[f1], be0 = lnb[f0], be1 = lnb[f1];

  for (int node = wid; node < N; node += nwav) {
    const size_t b = (size_t)node * F;
    float x0 = x[b + f0], x1 = x[b + f1];
    float h0 = out[b + f0] * sc0 + sh0 + x0;
    float h1 = out[b + f1] * sc1 + sh1 + x1;
    float s = h0 + h1, q = h0 * h0 + h1 * h1;
    #pragma unroll
    for (int o = 32; o > 0; o >>= 1) {
      s += __shfl_xor(s, o, 64);
      q += __shfl_xor(q, o, 64);
    }
    float mu = s * (1.f / 128.f);
    float var = q * (1.f / 128.f) - mu * mu;
    float rs = rsqrtf(var + EPS);
    float y0 = fmaxf((h0 - mu) * rs * g0 + be0, 0.f) + x0;
    float y1 = fmaxf((h1 - mu) * rs * g1 + be1, 0.f) + x1;
    out[b + f0] = y0;
    out[b + f1] = y1;
  }
}

// ---------------------------------------------------------------------------
extern "C" void kernel_launch(void* const* d_in, const int* in_sizes, int n_in,
                              void* d_out, int out_size, void* d_ws, size_t ws_size,
                              hipStream_t stream)
{
  const float* x   = (const float*)d_in[0];
  const int*   ei  = (const int*)d_in[1];
  const float* ea  = (const float*)d_in[2];
  const float* Wf  = (const float*)d_in[3];
  const float* bf  = (const float*)d_in[4];
  const float* Ws  = (const float*)d_in[5];
  const float* bs  = (const float*)d_in[6];
  const float* bng = (const float*)d_in[7];
  const float* bnb = (const float*)d_in[8];
  const float* lng = (const float*)d_in[9];
  const float* lnb = (const float*)d_in[10];

  const int N = in_sizes[0] / F;
  const int E = in_sizes[1] / 2;
  const int* srcA = ei;
  const int* dstA = ei + E;
  float* out = (float*)d_out;

  char* w = (char*)d_ws;
  size_t off = 0;
  auto up = [](size_t v) { return (v + 255) & ~(size_t)255; };
  float*  tabdst = (float*)(w + off);  off = up(off + (size_t)N * 256 * sizeof(float));
  uint32* tabsrc = (uint32*)(w + off); off = up(off + (size_t)N * F * sizeof(uint32));
  int*    srcs   = (int*)(w + off);    off = up(off + ((size_t)E + 16) * sizeof(int));
  int*    dstp   = (int*)(w + off);    off = up(off + ((size_t)E + 16) * sizeof(int));
  int*    cursor = (int*)(w + off);    off = up(off + (size_t)N * sizeof(int));
  int*    cnt    = (int*)(w + off);    off = up(off + (size_t)N * sizeof(int));
  float*  sums   = (float*)(w + off);  off = up(off + 256 * sizeof(float));
  // stg (N*256 f32) and eap (E*16 f32) share one region: stg consumed by
  // pack_src before fill_csr2 writes eap (same stream, serialized).
  float*  stg    = (float*)(w + off);
  float*  eap    = (float*)(w + off);

  hipMemsetAsync(cnt, 0, (size_t)N * sizeof(int), stream);
  hipMemsetAsync(sums, 0, 256 * sizeof(float), stream);
  hipMemsetAsync(out, 0, (size_t)N * F * sizeof(float), stream);

  node_gemm<<<dim3((N + 63) / 64, 8), 256, 0, stream>>>(x, Wf, Ws, bf, bs, tabdst, stg, N);
  pack_src<<<(N * F + 255) / 256, 256, 0, stream>>>(stg, tabsrc, N * F);
  count_deg<<<(E + 255) / 256, 256, 0, stream>>>(dstA, cnt, E);
  const int cpt = (N + 1023) / 1024;
  scan_k<<<1, 1024, 0, stream>>>(cnt, cursor, N, cpt);
  fill_csr2<<<(E + 255) / 256, 256, 0, stream>>>(dstA, srcA, ea, cursor, srcs, dstp, eap, E);

  int C = (E + 4095) / 4096;
  C = (C + 3) & ~3;                      // multiple of 4
  const int chunks = (E + C - 1) / C;
  const int waves = 2 * chunks;
  const int blocks = (waves + 3) / 4;
  aggregate_ebal<<<blocks, 256, 0, stream>>>(tabdst, tabsrc, eap, srcs, dstp, Wf, Ws, out, E, C);

  bn_stats<<<256, 256, 0, stream>>>(out, sums, N);
  finalize<<<(N + 3) / 4, 256, 0, stream>>>(x, out, sums, bng, bnb, lng, lnb, N);
}

// Round 5
// 410.513 us; speedup vs baseline: 1.1015x; 1.0765x over previous
//
#include <hip/hip_runtime.h>
#include <math.h>

#define F 128
#define ZD 272
#define EDIM 16
#define EPS 1e-5f

typedef unsigned int uint32;

__device__ __forceinline__ uint32 f2bf(float a) {
  uint32 u = __float_as_uint(a);
  u += 0x7FFF + ((u >> 16) & 1);   // RNE
  return u >> 16;
}

// ---------------------------------------------------------------------------
// Kernel A: node tables.
//   tabdst[n][f] = float2 {dst-filter(+bf), dst-softplus(+bs)} interleaved
//   stg[n][0:128) srcF, stg[n][128:256) srcS  (staging, packed by pack_src)
// ---------------------------------------------------------------------------
__global__ __launch_bounds__(256) void node_gemm(
    const float* __restrict__ x, const float* __restrict__ Wf,
    const float* __restrict__ Ws, const float* __restrict__ bf,
    const float* __restrict__ bs, float* __restrict__ tabdst,
    float* __restrict__ stg, int N)
{
  __shared__ float As[64][76];  // [k][m]
  __shared__ float Bs[64][76];  // [k][n]
  const int bm = blockIdx.x, bn = blockIdx.y;
  const int t = bn >> 1;                 // 0..3
  const int fbase = (bn & 1) * 64;       // 0 or 64
  const float* W = (t & 1) ? Ws : Wf;
  const int koff = (t >= 2) ? F : 0;
  const int tid = threadIdx.x;
  const int kq = (tid & 15) * 4;
  const int rr = tid >> 4;

  const int tx = tid & 15, ty = tid >> 4;
  const int m0 = ty * 4, n0 = tx * 4;
  float acc[4][4] = {};

  for (int kk = 0; kk < F; kk += 64) {
    #pragma unroll
    for (int it = 0; it < 4; ++it) {
      int row = it * 16 + rr;
      int node = bm * 64 + row;
      float4 v = make_float4(0.f, 0.f, 0.f, 0.f);
      if (node < N) v = *(const float4*)(x + (size_t)node * F + kk + kq);
      As[kq + 0][row] = v.x; As[kq + 1][row] = v.y;
      As[kq + 2][row] = v.z; As[kq + 3][row] = v.w;
    }
    #pragma unroll
    for (int it = 0; it < 4; ++it) {
      int n = it * 16 + rr;
      float4 v = *(const float4*)(W + (size_t)(fbase + n) * ZD + koff + kk + kq);
      Bs[kq + 0][n] = v.x; Bs[kq + 1][n] = v.y;
      Bs[kq + 2][n] = v.z; Bs[kq + 3][n] = v.w;
    }
    __syncthreads();
    #pragma unroll 8
    for (int k = 0; k < 64; ++k) {
      float4 a = *(const float4*)&As[k][m0];
      float4 b = *(const float4*)&Bs[k][n0];
      float av[4] = {a.x, a.y, a.z, a.w};
      float bv[4] = {b.x, b.y, b.z, b.w};
      #pragma unroll
      for (int i = 0; i < 4; ++i)
        #pragma unroll
        for (int j = 0; j < 4; ++j)
          acc[i][j] += av[i] * bv[j];
    }
    __syncthreads();
  }

  #pragma unroll
  for (int i = 0; i < 4; ++i) {
    int node = bm * 64 + m0 + i;
    if (node >= N) continue;
    const size_t nb = (size_t)node * 256;
    #pragma unroll
    for (int j = 0; j < 4; ++j) {
      int f = fbase + n0 + j;
      float v = acc[i][j];
      if (t == 0)      tabdst[((size_t)node * F + f) * 2]     = v + bf[f];
      else if (t == 1) tabdst[((size_t)node * F + f) * 2 + 1] = v + bs[f];
      else if (t == 2) stg[nb + f] = v;
      else             stg[nb + F + f] = v;
    }
  }
}

// Pack src tables: {srcF,srcS} -> one u32 of two bf16
__global__ __launch_bounds__(256) void pack_src(
    const float* __restrict__ stg, uint32* __restrict__ tabsrc, int total)
{
  int i = blockIdx.x * blockDim.x + threadIdx.x;
  if (i < total) {
    int n = i >> 7, f = i & 127;
    float sf = stg[(size_t)n * 256 + f];
    float ss = stg[(size_t)n * 256 + F + f];
    tabsrc[i] = f2bf(sf) | (f2bf(ss) << 16);
  }
}

// ---------------------------------------------------------------------------
// CSR build
// ---------------------------------------------------------------------------
__global__ void count_deg(const int* __restrict__ dst, int* __restrict__ cnt, int E)
{
  int e = blockIdx.x * blockDim.x + threadIdx.x;
  if (e < E) atomicAdd(&cnt[dst[e]], 1);
}

__global__ __launch_bounds__(1024) void scan_k(
    const int* __restrict__ cnt, int* __restrict__ cursor, int N, int cpt)
{
  __shared__ int lds[1024];
  const int tid = threadIdx.x;
  const int base = tid * cpt;
  int run = 0;
  for (int j = 0; j < cpt; ++j) {
    int idx = base + j;
    run += (idx < N) ? cnt[idx] : 0;
  }
  lds[tid] = run;
  __syncthreads();
  for (int off = 1; off < 1024; off <<= 1) {
    int v = (tid >= off) ? lds[tid - off] : 0;
    __syncthreads();
    lds[tid] += v;
    __syncthreads();
  }
  int v = lds[tid] - run;
  for (int j = 0; j < cpt; ++j) {
    int idx = base + j;
    if (idx < N) { cursor[idx] = v; v += cnt[idx]; }
  }
}

// Permuting fill: {src,dst} pairs + edge-attr into CSR (dst-sorted) order
__global__ void fill_csr2(const int* __restrict__ dst, const int* __restrict__ srcA,
                          const float* __restrict__ ea, int* __restrict__ cursor,
                          int2* __restrict__ sd, float* __restrict__ eap, int E)
{
  int e = blockIdx.x * blockDim.x + threadIdx.x;
  if (e < E) {
    int d = dst[e];
    int pos = atomicAdd(&cursor[d], 1);
    sd[pos] = make_int2(srcA[e], d);
    const float4* s4 = (const float4*)(ea + (size_t)e * EDIM);
    float4 a = s4[0], b = s4[1], c = s4[2], dd = s4[3];
    float4* d4 = (float4*)(eap + (size_t)pos * EDIM);
    d4[0] = a; d4[1] = b; d4[2] = c; d4[3] = dd;
  }
}

// ---------------------------------------------------------------------------
// Aggregation: edge-balanced, packed-f32 math, 32-bit addressing.
// ---------------------------------------------------------------------------
__device__ __forceinline__ float sigm(float v) {
  return __builtin_amdgcn_rcpf(1.f + __expf(-v));
}
__device__ __forceinline__ float splus(float v) {
  return fmaxf(v, 0.f) + __logf(1.f + __expf(-fabsf(v)));
}

__device__ __forceinline__ float edge_term(
    uint32 pk, float2 pdfs, const float4* __restrict__ e4, const float2* w2)
{
  float2 a2 = make_float2(pdfs.x + __uint_as_float(pk << 16),
                          pdfs.y + __uint_as_float(pk & 0xFFFF0000u));
  #pragma unroll
  for (int q = 0; q < 4; ++q) {
    float4 v = e4[q];
    a2.x += w2[4*q+0].x*v.x + w2[4*q+1].x*v.y + w2[4*q+2].x*v.z + w2[4*q+3].x*v.w;
    a2.y += w2[4*q+0].y*v.x + w2[4*q+1].y*v.y + w2[4*q+2].y*v.z + w2[4*q+3].y*v.w;
  }
  return sigm(a2.x) * splus(a2.y);
}

__global__ __launch_bounds__(256, 4) void aggregate_ebal(
    const float* __restrict__ tabdst, const uint32* __restrict__ tabsrc,
    const float4* __restrict__ eap4, const int2* __restrict__ sd,
    const float* __restrict__ Wf, const float* __restrict__ Ws,
    float* __restrict__ agg, int E, int C)
{
  const int lane = threadIdx.x & 63;
  const int wid  = (blockIdx.x * blockDim.x + threadIdx.x) >> 6;
  const int half = wid & 1;
  const int chunk = wid >> 1;
  const int p0 = chunk * C;
  if (p0 >= E) return;
  int p1 = p0 + C; if (p1 > E) p1 = E;
  const uint32 f = (uint32)((half << 6) | lane);

  float2 w2[16];
  #pragma unroll
  for (int q = 0; q < 4; ++q) {
    float4 a = ((const float4*)(Wf + (size_t)f * ZD + 2 * F))[q];
    float4 b = ((const float4*)(Ws + (size_t)f * ZD + 2 * F))[q];
    w2[4*q+0] = make_float2(a.x, b.x);
    w2[4*q+1] = make_float2(a.y, b.y);
    w2[4*q+2] = make_float2(a.z, b.z);
    w2[4*q+3] = make_float2(a.w, b.w);
  }

  const int4* sd4 = (const int4*)sd;   // one int4 = 2 edges {s,d,s,d}

  // prologue: current batch sd + gathers, next batch sd
  int4 cu = sd4[(p0 >> 1)], cv = sd4[(p0 >> 1) + 1];
  uint32 svc[4], svn[4];
  svc[0] = tabsrc[(uint32)cu.x * F + f];
  svc[1] = tabsrc[(uint32)cu.z * F + f];
  svc[2] = tabsrc[(uint32)cv.x * F + f];
  svc[3] = tabsrc[(uint32)cv.z * F + f];
  int4 nu = sd4[(p0 >> 1) + 2], nv = sd4[(p0 >> 1) + 3];

  int curDst = cu.y;
  float2 pdfs = *(const float2*)(tabdst + (uint32)curDst * 256u + 2u * f);
  float acc = 0.f;

  const int nmain = (p1 - p0) & ~3;
  int p = p0;
  for (; p < p0 + nmain; p += 4) {
    // prefetch next batch's gathers + batch-after-next sd
    svn[0] = tabsrc[(uint32)nu.x * F + f];
    svn[1] = tabsrc[(uint32)nu.z * F + f];
    svn[2] = tabsrc[(uint32)nv.x * F + f];
    svn[3] = tabsrc[(uint32)nv.z * F + f];
    int4 fu = sd4[(p >> 1) + 4], fv = sd4[(p >> 1) + 5];

    const int ds[4] = {cu.y, cu.w, cv.y, cv.w};
    const float4* e4 = eap4 + (uint32)p * 4u;
    #pragma unroll
    for (int i = 0; i < 4; ++i) {
      if (ds[i] != curDst) {               // wave-uniform branch
        atomicAdd(&agg[(uint32)curDst * F + f], acc);
        acc = 0.f; curDst = ds[i];
        pdfs = *(const float2*)(tabdst + (uint32)curDst * 256u + 2u * f);
      }
      acc += edge_term(svc[i], pdfs, e4 + 4 * i, w2);
    }

    svc[0] = svn[0]; svc[1] = svn[1]; svc[2] = svn[2]; svc[3] = svn[3];
    cu = nu; cv = nv; nu = fu; nv = fv;
  }
  // tail (< 4 edges)
  for (; p < p1; ++p) {
    int2 e2 = sd[p];
    if (e2.y != curDst) {
      atomicAdd(&agg[(uint32)curDst * F + f], acc);
      acc = 0.f; curDst = e2.y;
      pdfs = *(const float2*)(tabdst + (uint32)curDst * 256u + 2u * f);
    }
    uint32 pk = tabsrc[(uint32)e2.x * F + f];
    acc += edge_term(pk, pdfs, eap4 + (uint32)p * 4u, w2);
  }
  atomicAdd(&agg[(uint32)curDst * F + f], acc);
}

// ---------------------------------------------------------------------------
__global__ __launch_bounds__(256) void bn_stats(
    const float* __restrict__ agg, float* __restrict__ sums, int N)
{
  const int f = threadIdx.x & 127;
  const int h = threadIdx.x >> 7;
  float s = 0.f, ss = 0.f;
  for (int r = blockIdx.x * 2 + h; r < N; r += gridDim.x * 2) {
    float v = agg[(size_t)r * F + f];
    s += v; ss += v * v;
  }
  atomicAdd(&sums[f], s);
  atomicAdd(&sums[F + f], ss);
}

__global__ __launch_bounds__(256) void finalize(
    const float* __restrict__ x, float* __restrict__ out,
    const float* __restrict__ sums, const float* __restrict__ bng,
    const float* __restrict__ bnb, const float* __restrict__ lng,
    const float* __restrict__ lnb, int N)
{
  const int lane = threadIdx.x & 63;
  const int wid  = (blockIdx.x * blockDim.x + threadIdx.x) >> 6;
  const int nwav = (gridDim.x * blockDim.x) >> 6;
  const int f0 = lane, f1 = lane + 64;
  const float invN = 1.f / (float)N;

  float mu0 = sums[f0] * invN, vv0 = sums[F + f0] * invN - mu0 * mu0;
  float mu1 = sums[f1] * invN, vv1 = sums[F + f1] * invN - mu1 * mu1;
  float sc0 = rsqrtf(vv0 + EPS) * bng[f0], sh0 = bnb[f0] - mu0 * sc0;
  float sc1 = rsqrtf(vv1 + EPS) * bng[f1], sh1 = bnb[f1] - mu1 * sc1;
  float g0 = lng[f0], g1 = lng[f1], be0 = lnb[f0], be1 = lnb[f1];

  for (int node = wid; node < N; node += nwav) {
    const size_t b = (size_t)node * F;
    float x0 = x[b + f0], x1 = x[b + f1];
    float h0 = out[b + f0] * sc0 + sh0 + x0;
    float h1 = out[b + f1] * sc1 + sh1 + x1;
    float s = h0 + h1, q = h0 * h0 + h1 * h1;
    #pragma unroll
    for (int o = 32; o > 0; o >>= 1) {
      s += __shfl_xor(s, o, 64);
      q += __shfl_xor(q, o, 64);
    }
    float mu = s * (1.f / 128.f);
    float var = q * (1.f / 128.f) - mu * mu;
    float rs = rsqrtf(var + EPS);
    float y0 = fmaxf((h0 - mu) * rs * g0 + be0, 0.f) + x0;
    float y1 = fmaxf((h1 - mu) * rs * g1 + be1, 0.f) + x1;
    out[b + f0] = y0;
    out[b + f1] = y1;
  }
}

// ---------------------------------------------------------------------------
extern "C" void kernel_launch(void* const* d_in, const int* in_sizes, int n_in,
                              void* d_out, int out_size, void* d_ws, size_t ws_size,
                              hipStream_t stream)
{
  const float* x   = (const float*)d_in[0];
  const int*   ei  = (const int*)d_in[1];
  const float* ea  = (const float*)d_in[2];
  const float* Wf  = (const float*)d_in[3];
  const float* bf  = (const float*)d_in[4];
  const float* Ws  = (const float*)d_in[5];
  const float* bs  = (const float*)d_in[6];
  const float* bng = (const float*)d_in[7];
  const float* bnb = (const float*)d_in[8];
  const float* lng = (const float*)d_in[9];
  const float* lnb = (const float*)d_in[10];

  const int N = in_sizes[0] / F;
  const int E = in_sizes[1] / 2;
  const int* srcA = ei;
  const int* dstA = ei + E;
  float* out = (float*)d_out;

  char* w = (char*)d_ws;
  size_t off = 0;
  auto up = [](size_t v) { return (v + 255) & ~(size_t)255; };
  float*  tabdst = (float*)(w + off);  off = up(off + (size_t)N * 256 * sizeof(float));
  uint32* tabsrc = (uint32*)(w + off); off = up(off + (size_t)N * F * sizeof(uint32));
  int2*   sd     = (int2*)(w + off);   off = up(off + ((size_t)E + 32) * sizeof(int2));
  int*    cursor = (int*)(w + off);    off = up(off + (size_t)N * sizeof(int));
  int*    cnt    = (int*)(w + off);    off = up(off + (size_t)N * sizeof(int));
  float*  sums   = (float*)(w + off);  off = up(off + 256 * sizeof(float));
  // stg (N*256 f32) and eap (E*16 f32) share one region: stg fully consumed
  // by pack_src before fill_csr2 writes eap (stream-ordered).
  float*  stg    = (float*)(w + off);
  float*  eap    = (float*)(w + off);

  hipMemsetAsync(cnt, 0, (size_t)N * sizeof(int), stream);
  hipMemsetAsync(sums, 0, 256 * sizeof(float), stream);
  hipMemsetAsync(sd + E, 0, 32 * sizeof(int2), stream);
  hipMemsetAsync(out, 0, (size_t)N * F * sizeof(float), stream);

  node_gemm<<<dim3((N + 63) / 64, 8), 256, 0, stream>>>(x, Wf, Ws, bf, bs, tabdst, stg, N);
  pack_src<<<(N * F + 255) / 256, 256, 0, stream>>>(stg, tabsrc, N * F);
  count_deg<<<(E + 255) / 256, 256, 0, stream>>>(dstA, cnt, E);
  const int cpt = (N + 1023) / 1024;
  scan_k<<<1, 1024, 0, stream>>>(cnt, cursor, N, cpt);
  fill_csr2<<<(E + 255) / 256, 256, 0, stream>>>(dstA, srcA, ea, cursor, sd, eap, E);

  const int C = 64;
  const int chunks = (E + C - 1) / C;
  const int waves = 2 * chunks;
  const int blocks = (waves + 3) / 4;
  aggregate_ebal<<<blocks, 256, 0, stream>>>(tabdst, tabsrc, (const float4*)eap, sd, Wf, Ws, out, E, C);

  bn_stats<<<256, 256, 0, stream>>>(out, sums, N);
  finalize<<<(N + 3) / 4, 256, 0, stream>>>(x, out, sums, bng, bnb, lng, lnb, N);
}

// Round 6
// 318.288 us; speedup vs baseline: 1.4207x; 1.2898x over previous
//
#include <hip/hip_runtime.h>
#include <math.h>

#define F 128
#define ZD 272
#define EDIM 16
#define EPS 1e-5f
#define CHK 64           // edges per chunk (one wave-pair)

typedef unsigned int u32;
typedef float v2f __attribute__((ext_vector_type(2)));

__device__ __forceinline__ u32 f2bf(float a) {
  u32 u = __float_as_uint(a);
  u += 0x7FFF + ((u >> 16) & 1);   // RNE
  return u >> 16;
}

// ---------------------------------------------------------------------------
// Kernel A: node tables.
//   tabdst[n][f] = float2 {dst-filter(+bf), dst-softplus(+bs)} interleaved f32
//   tabsrc[n][f] = u32 {bf16 srcF | bf16 srcS<<16}, halves written directly
// ---------------------------------------------------------------------------
__global__ __launch_bounds__(256) void node_gemm(
    const float* __restrict__ x, const float* __restrict__ Wf,
    const float* __restrict__ Ws, const float* __restrict__ bf,
    const float* __restrict__ bs, float* __restrict__ tabdst,
    unsigned short* __restrict__ tabsrc16, int N)
{
  __shared__ float As[64][76];  // [k][m]
  __shared__ float Bs[64][76];  // [k][n]
  const int bm = blockIdx.x, bn = blockIdx.y;
  const int t = bn >> 1;                 // 0..3
  const int fbase = (bn & 1) * 64;       // 0 or 64
  const float* W = (t & 1) ? Ws : Wf;
  const int koff = (t >= 2) ? F : 0;
  const int tid = threadIdx.x;
  const int kq = (tid & 15) * 4;
  const int rr = tid >> 4;

  const int tx = tid & 15, ty = tid >> 4;
  const int m0 = ty * 4, n0 = tx * 4;
  float acc[4][4] = {};

  for (int kk = 0; kk < F; kk += 64) {
    #pragma unroll
    for (int it = 0; it < 4; ++it) {
      int row = it * 16 + rr;
      int node = bm * 64 + row;
      float4 v = make_float4(0.f, 0.f, 0.f, 0.f);
      if (node < N) v = *(const float4*)(x + (size_t)node * F + kk + kq);
      As[kq + 0][row] = v.x; As[kq + 1][row] = v.y;
      As[kq + 2][row] = v.z; As[kq + 3][row] = v.w;
    }
    #pragma unroll
    for (int it = 0; it < 4; ++it) {
      int n = it * 16 + rr;
      float4 v = *(const float4*)(W + (size_t)(fbase + n) * ZD + koff + kk + kq);
      Bs[kq + 0][n] = v.x; Bs[kq + 1][n] = v.y;
      Bs[kq + 2][n] = v.z; Bs[kq + 3][n] = v.w;
    }
    __syncthreads();
    #pragma unroll 8
    for (int k = 0; k < 64; ++k) {
      float4 a = *(const float4*)&As[k][m0];
      float4 b = *(const float4*)&Bs[k][n0];
      float av[4] = {a.x, a.y, a.z, a.w};
      float bv[4] = {b.x, b.y, b.z, b.w};
      #pragma unroll
      for (int i = 0; i < 4; ++i)
        #pragma unroll
        for (int j = 0; j < 4; ++j)
          acc[i][j] += av[i] * bv[j];
    }
    __syncthreads();
  }

  #pragma unroll
  for (int i = 0; i < 4; ++i) {
    int node = bm * 64 + m0 + i;
    if (node >= N) continue;
    #pragma unroll
    for (int j = 0; j < 4; ++j) {
      int fcol = fbase + n0 + j;
      float v = acc[i][j];
      size_t idx = ((size_t)node * F + fcol) * 2;
      if (t == 0)      tabdst[idx]     = v + bf[fcol];
      else if (t == 1) tabdst[idx + 1] = v + bs[fcol];
      else if (t == 2) tabsrc16[idx]     = (unsigned short)f2bf(v);
      else             tabsrc16[idx + 1] = (unsigned short)f2bf(v);
    }
  }
}

// ---------------------------------------------------------------------------
// CSR build
// ---------------------------------------------------------------------------
__global__ void count_deg(const int* __restrict__ dst, int* __restrict__ cnt, int E)
{
  int e = blockIdx.x * blockDim.x + threadIdx.x;
  if (e < E) atomicAdd(&cnt[dst[e]], 1);
}

__global__ __launch_bounds__(1024) void scan_k(
    const int* __restrict__ cnt, int* __restrict__ cursor, int N, int cpt)
{
  __shared__ int lds[1024];
  const int tid = threadIdx.x;
  const int base = tid * cpt;
  int run = 0;
  for (int j = 0; j < cpt; ++j) {
    int idx = base + j;
    run += (idx < N) ? cnt[idx] : 0;
  }
  lds[tid] = run;
  __syncthreads();
  for (int off = 1; off < 1024; off <<= 1) {
    int v = (tid >= off) ? lds[tid - off] : 0;
    __syncthreads();
    lds[tid] += v;
    __syncthreads();
  }
  int v = lds[tid] - run;
  for (int j = 0; j < cpt; ++j) {
    int idx = base + j;
    if (idx < N) { cursor[idx] = v; v += cnt[idx]; }
  }
}

__global__ void fill_csr2(const int* __restrict__ dst, const int* __restrict__ srcA,
                          const float* __restrict__ ea, int* __restrict__ cursor,
                          int2* __restrict__ sd, float* __restrict__ eap, int E)
{
  int e = blockIdx.x * blockDim.x + threadIdx.x;
  if (e < E) {
    int d = dst[e];
    int pos = atomicAdd(&cursor[d], 1);
    sd[pos] = make_int2(srcA[e], d);
    const float4* s4 = (const float4*)(ea + (size_t)e * EDIM);
    float4 a = s4[0], b = s4[1], c = s4[2], dd = s4[3];
    float4* d4 = (float4*)(eap + (size_t)pos * EDIM);
    d4[0] = a; d4[1] = b; d4[2] = c; d4[3] = dd;
  }
}

// ---------------------------------------------------------------------------
// Aggregation: wave-pair per 64-edge chunk. ea staged to LDS asynchronously
// (global_load_lds), tabsrc gathers pipelined one 8-edge group ahead.
// ---------------------------------------------------------------------------
__device__ __forceinline__ float sigm(float v) {
  return __builtin_amdgcn_rcpf(1.f + __expf(-v));
}
__device__ __forceinline__ float splus(float v) {
  return fmaxf(v, 0.f) + __logf(1.f + __expf(-fabsf(v)));
}

struct G8 { int4 a, b, c, d; };   // 8 edges of {src,dst}

__device__ __forceinline__ void gload(G8& g, const int4* p) {
  g.a = p[0]; g.b = p[1]; g.c = p[2]; g.d = p[3];
}
__device__ __forceinline__ void gather8(u32* sv, const G8& g,
                                        const u32* __restrict__ tabsrc, u32 f) {
  sv[0] = tabsrc[(u32)g.a.x * F + f]; sv[1] = tabsrc[(u32)g.a.z * F + f];
  sv[2] = tabsrc[(u32)g.b.x * F + f]; sv[3] = tabsrc[(u32)g.b.z * F + f];
  sv[4] = tabsrc[(u32)g.c.x * F + f]; sv[5] = tabsrc[(u32)g.c.z * F + f];
  sv[6] = tabsrc[(u32)g.d.x * F + f]; sv[7] = tabsrc[(u32)g.d.z * F + f];
}
__device__ __forceinline__ void dsts8(int* d, const G8& g) {
  d[0] = g.a.y; d[1] = g.a.w; d[2] = g.b.y; d[3] = g.b.w;
  d[4] = g.c.y; d[5] = g.c.w; d[6] = g.d.y; d[7] = g.d.w;
}

#define AS1 __attribute__((address_space(1)))
#define AS3 __attribute__((address_space(3)))
__device__ __forceinline__ void stage4k(const float4* g, float4* l, int lane) {
  __builtin_amdgcn_global_load_lds((AS1 const void*)(g + lane),       (AS3 void*)(l),       16, 0, 0);
  __builtin_amdgcn_global_load_lds((AS1 const void*)(g + 64 + lane),  (AS3 void*)(l + 64),  16, 0, 0);
  __builtin_amdgcn_global_load_lds((AS1 const void*)(g + 128 + lane), (AS3 void*)(l + 128), 16, 0, 0);
  __builtin_amdgcn_global_load_lds((AS1 const void*)(g + 192 + lane), (AS3 void*)(l + 192), 16, 0, 0);
}

__global__ __launch_bounds__(256, 4) void aggregate_lds(
    const float* __restrict__ tabdst, const u32* __restrict__ tabsrc,
    const float4* __restrict__ eap4, const int4* __restrict__ sd4,
    const float* __restrict__ Wf, const float* __restrict__ Ws,
    float* __restrict__ agg, int E)
{
  __shared__ float4 eabuf[2][256];         // 2 pairs x 64 edges x 64B = 8KB
  const int tid  = threadIdx.x;
  const int lane = tid & 63;
  const int wib  = tid >> 6;               // 0..3
  const int pair = wib >> 1;               // 0..1
  const int half = wib & 1;
  const int chunk = blockIdx.x * 2 + pair;
  const int p0 = chunk * CHK;
  const u32 f = (u32)((half << 6) | lane);

  // per-feature ea weights, packed {wf, ws}
  v2f w2[16];
  #pragma unroll
  for (int q = 0; q < 4; ++q) {
    float4 a = ((const float4*)(Wf + (size_t)f * ZD + 2 * F))[q];
    float4 b = ((const float4*)(Ws + (size_t)f * ZD + 2 * F))[q];
    w2[4*q+0] = (v2f){a.x, b.x};
    w2[4*q+1] = (v2f){a.y, b.y};
    w2[4*q+2] = (v2f){a.z, b.z};
    w2[4*q+3] = (v2f){a.w, b.w};
  }

  float4* lb0 = &eabuf[pair][0];
  if (half == 0) stage4k(eap4 + (size_t)p0 * 4, lb0, lane);  // async ea chunk

  const int sdb = p0 >> 1;                 // int4 index; group g at sdb + g*4
  G8 cur, nxt;
  gload(cur, sd4 + sdb);                   // group 0
  u32 svc[8];
  gather8(svc, cur, tabsrc, f);            // gathers group 0
  int dc[8];
  dsts8(dc, cur);
  gload(nxt, sd4 + sdb + 4);               // group 1

  int curDst = dc[0];
  v2f pdfs = *(const v2f*)(tabdst + (u32)curDst * 256u + 2u * f);
  float acc = 0.f;
  const int lim = E - p0;                  // valid-edge bound within chunk

  __syncthreads();                         // ea staged (vmcnt drained by producer)

  #pragma unroll
  for (int it = 0; it < 8; ++it) {
    // pipeline: gathers for group it+1, sd for group it+2
    u32 svn[8];
    gather8(svn, nxt, tabsrc, f);
    int dn[8];
    dsts8(dn, nxt);
    gload(nxt, sd4 + sdb + (it + 2) * 4);  // pad-covered beyond chunk

    const float4* lb = lb0 + it * 32;
    #pragma unroll
    for (int i = 0; i < 8; ++i) {
      int d = dc[i];
      if (d != curDst) {                   // value-uniform across wave
        atomicAdd(&agg[(u32)curDst * F + f], acc);
        acc = 0.f; curDst = d;
        pdfs = *(const v2f*)(tabdst + (u32)d * 256u + 2u * f);
      }
      float4 q0 = lb[i*4+0], q1 = lb[i*4+1], q2 = lb[i*4+2], q3 = lb[i*4+3];
      u32 pk = svc[i];
      v2f a2 = pdfs + (v2f){__uint_as_float(pk << 16),
                            __uint_as_float(pk & 0xFFFF0000u)};
      a2 += w2[0]  * q0.x; a2 += w2[1]  * q0.y; a2 += w2[2]  * q0.z; a2 += w2[3]  * q0.w;
      a2 += w2[4]  * q1.x; a2 += w2[5]  * q1.y; a2 += w2[6]  * q1.z; a2 += w2[7]  * q1.w;
      a2 += w2[8]  * q2.x; a2 += w2[9]  * q2.y; a2 += w2[10] * q2.z; a2 += w2[11] * q2.w;
      a2 += w2[12] * q3.x; a2 += w2[13] * q3.y; a2 += w2[14] * q3.z; a2 += w2[15] * q3.w;
      float term = sigm(a2.x) * splus(a2.y);
      acc += ((it * 8 + i) < lim) ? term : 0.f;
    }
    #pragma unroll
    for (int i = 0; i < 8; ++i) { svc[i] = svn[i]; dc[i] = dn[i]; }
  }
  atomicAdd(&agg[(u32)curDst * F + f], acc);
}

// ---------------------------------------------------------------------------
__global__ __launch_bounds__(256) void bn_stats(
    const float* __restrict__ agg, float* __restrict__ sums, int N)
{
  const int f = threadIdx.x & 127;
  const int h = threadIdx.x >> 7;
  float s = 0.f, ss = 0.f;
  for (int r = blockIdx.x * 2 + h; r < N; r += gridDim.x * 2) {
    float v = agg[(size_t)r * F + f];
    s += v; ss += v * v;
  }
  atomicAdd(&sums[f], s);
  atomicAdd(&sums[F + f], ss);
}

__global__ __launch_bounds__(256) void finalize(
    const float* __restrict__ x, float* __restrict__ out,
    const float* __restrict__ sums, const float* __restrict__ bng,
    const float* __restrict__ bnb, const float* __restrict__ lng,
    const float* __restrict__ lnb, int N)
{
  const int lane = threadIdx.x & 63;
  const int wid  = (blockIdx.x * blockDim.x + threadIdx.x) >> 6;
  const int nwav = (gridDim.x * blockDim.x) >> 6;
  const int f0 = lane, f1 = lane + 64;
  const float invN = 1.f / (float)N;

  float mu0 = sums[f0] * invN, vv0 = sums[F + f0] * invN - mu0 * mu0;
  float mu1 = sums[f1] * invN, vv1 = sums[F + f1] * invN - mu1 * mu1;
  float sc0 = rsqrtf(vv0 + EPS) * bng[f0], sh0 = bnb[f0] - mu0 * sc0;
  float sc1 = rsqrtf(vv1 + EPS) * bng[f1], sh1 = bnb[f1] - mu1 * sc1;
  float g0 = lng[f0], g1 = lng[f1], be0 = lnb[f0], be1 = lnb[f1];

  for (int node = wid; node < N; node += nwav) {
    const size_t b = (size_t)node * F;
    float x0 = x[b + f0], x1 = x[b + f1];
    float h0 = out[b + f0] * sc0 + sh0 + x0;
    float h1 = out[b + f1] * sc1 + sh1 + x1;
    float s = h0 + h1, q = h0 * h0 + h1 * h1;
    #pragma unroll
    for (int o = 32; o > 0; o >>= 1) {
      s += __shfl_xor(s, o, 64);
      q += __shfl_xor(q, o, 64);
    }
    float mu = s * (1.f / 128.f);
    float var = q * (1.f / 128.f) - mu * mu;
    float rs = rsqrtf(var + EPS);
    float y0 = fmaxf((h0 - mu) * rs * g0 + be0, 0.f) + x0;
    float y1 = fmaxf((h1 - mu) * rs * g1 + be1, 0.f) + x1;
    out[b + f0] = y0;
    out[b + f1] = y1;
  }
}

// ---------------------------------------------------------------------------
extern "C" void kernel_launch(void* const* d_in, const int* in_sizes, int n_in,
                              void* d_out, int out_size, void* d_ws, size_t ws_size,
                              hipStream_t stream)
{
  const float* x   = (const float*)d_in[0];
  const int*   ei  = (const int*)d_in[1];
  const float* ea  = (const float*)d_in[2];
  const float* Wf  = (const float*)d_in[3];
  const float* bf  = (const float*)d_in[4];
  const float* Ws  = (const float*)d_in[5];
  const float* bs  = (const float*)d_in[6];
  const float* bng = (const float*)d_in[7];
  const float* bnb = (const float*)d_in[8];
  const float* lng = (const float*)d_in[9];
  const float* lnb = (const float*)d_in[10];

  const int N = in_sizes[0] / F;
  const int E = in_sizes[1] / 2;
  const int* srcA = ei;
  const int* dstA = ei + E;
  float* out = (float*)d_out;

  const int chunks = (E + CHK - 1) / CHK;
  const int chunksEven = (chunks + 1) & ~1;
  const int Epad = chunksEven * CHK + 128;   // sd lookahead + stage pad

  char* w = (char*)d_ws;
  size_t off = 0;
  auto up = [](size_t v) { return (v + 255) & ~(size_t)255; };
  float*  tabdst = (float*)(w + off);  off = up(off + (size_t)N * 256 * sizeof(float));
  u32*    tabsrc = (u32*)(w + off);    off = up(off + (size_t)N * F * sizeof(u32));
  int2*   sd     = (int2*)(w + off);   off = up(off + (size_t)Epad * sizeof(int2));
  int*    cursor = (int*)(w + off);    off = up(off + (size_t)N * sizeof(int));
  int*    cnt    = (int*)(w + off);    off = up(off + (size_t)N * sizeof(int));
  float*  sums   = (float*)(w + off);  off = up(off + 256 * sizeof(float));
  float*  eap    = (float*)(w + off);  off = up(off + (size_t)Epad * EDIM * sizeof(float));

  hipMemsetAsync(cnt, 0, (size_t)N * sizeof(int), stream);
  hipMemsetAsync(sums, 0, 256 * sizeof(float), stream);
  hipMemsetAsync(sd + E, 0, (size_t)(Epad - E) * sizeof(int2), stream);
  hipMemsetAsync(eap + (size_t)E * EDIM, 0,
                 (size_t)(Epad - E) * EDIM * sizeof(float), stream);
  hipMemsetAsync(out, 0, (size_t)N * F * sizeof(float), stream);

  node_gemm<<<dim3((N + 63) / 64, 8), 256, 0, stream>>>(
      x, Wf, Ws, bf, bs, tabdst, (unsigned short*)tabsrc, N);
  count_deg<<<(E + 255) / 256, 256, 0, stream>>>(dstA, cnt, E);
  const int cpt = (N + 1023) / 1024;
  scan_k<<<1, 1024, 0, stream>>>(cnt, cursor, N, cpt);
  fill_csr2<<<(E + 255) / 256, 256, 0, stream>>>(dstA, srcA, ea, cursor, sd, eap, E);

  aggregate_lds<<<chunksEven / 2, 256, 0, stream>>>(
      tabdst, tabsrc, (const float4*)eap, (const int4*)sd, Wf, Ws, out, E);

  bn_stats<<<256, 256, 0, stream>>>(out, sums, N);
  finalize<<<(N + 3) / 4, 256, 0, stream>>>(x, out, sums, bng, bnb, lng, lnb, N);
}